// Round 4
// baseline (368.343 us; speedup 1.0000x reference)
//
#include <hip/hip_runtime.h>
#include <hip/hip_bf16.h>

#define NN    1024
#define DD    128
#define BT    64     // tile dim (64x64 gram tile per block)
#define PITCH 136    // bf16 elems per LDS tile row (128 + 8 pad)
#define SQP   68     // f32 elems per LDS sq row (64 + 4 pad)
#define NBLK  4096   // 16 batches x 16x16 tiles

typedef __bf16 bf16_t;
typedef bf16_t bf16x8 __attribute__((ext_vector_type(8)));
typedef float  f32x4  __attribute__((ext_vector_type(4)));

// ws layout (floats):
// [0] coord_sum  [1] reg_sum  [2] count_loss_sum  [3] bce_sum
// [4+b] pos_sum  [20+b] pos_cnt  [36+b] neg_sum  [52+b] neg_cnt
// [68] ticket counter (as unsigned)  -> 69 floats, memset 276 B

__device__ __forceinline__ void loss_elem(float l, float a, float s, int grow, int gcol,
    float& bsum, float& poss, float& posc, float& negs, float& negc) {
  bsum += fmaxf(l, 0.f) - l * a + __logf(1.f + __expf(-fabsf(l)));
  if (a > 0.5f) {
    poss += s; posc += 1.f;
  } else if (grow != gcol) {
    negc += 1.f;
    if (s < 1.f) {                      // essentially never for random 128-d features
      float d = sqrtf(fmaxf(s, 1e-12f));
      float h = 1.f - d;
      negs += h * h;
    }
  }
}

__global__ __launch_bounds__(512, 6) void fused_all(
    const float* __restrict__ logits, const float* __restrict__ adj,
    const float* __restrict__ feat,   const float* __restrict__ pcoord,
    const float* __restrict__ pts,    const float* __restrict__ masks,
    const float* __restrict__ pcount, float* __restrict__ ws,
    float* __restrict__ out) {
  // lsA (17408 B) + lsB (17408 B); sqb (64*68*4 = 17408 B) overlays lsA post-MFMA
  __shared__ __align__(16) char smem[2 * BT * PITCH * sizeof(bf16_t)];
  bf16_t* lsA = (bf16_t*)smem;
  bf16_t* lsB = (bf16_t*)(smem + BT * PITCH * sizeof(bf16_t));
  float*  sqb = (float*)smem;
  __shared__ float nrmA[BT], nrmB[BT];
  __shared__ float red[8][8];

  const int bx  = blockIdx.x;
  const int b   = bx >> 8;            // 256 tiles per batch
  const int tid = bx & 255;
  const int ti  = (tid >> 4) << 6;    // tile row base
  const int tj  = (tid & 15) << 6;    // tile col base
  const bool diag    = (ti == tj);    // 16 per batch: partition rows for reg_loss
  const bool special = (tid == 0);    // 1 per batch: coord/mask/count extras

  const int t = threadIdx.x;          // 0..511, 8 waves
  const float* fb = feat + (size_t)b * NN * DD;

  // ---- per-batch extras on special blocks (tiny, no barriers involved) ----
  float coordsum = 0.f, cntsum = 0.f;
  if (special) {
    const float4* a4 = (const float4*)(pcoord + (size_t)b * NN * 2);
    const float4* b4 = (const float4*)(pts    + (size_t)b * NN * 2);
    float4 ac = a4[t], bc = b4[t];    // 512 float4 per batch, one per thread
    float dx = ac.x-bc.x, dy = ac.y-bc.y, dz = ac.z-bc.z, dw = ac.w-bc.w;
    coordsum = dx*dx + dy*dy + dz*dz + dw*dw;
    const float* m = masks + b * NN;
    cntsum = m[t] + m[t + 512];
  }

  // ---- stage A rows [ti,ti+64) and B rows [tj,tj+64) as bf16 into LDS ----
  // Diagonal blocks accumulate fp32 sum(nf^2) from their A band (rows
  // partition the batch across the 16 diagonal blocks -> counted once).
  float regsum = 0.f;
  #pragma unroll
  for (int it = 0; it < 4; ++it) {
    int cid  = it * 512 + t;          // 0..2047 chunks of 8 floats
    int tile = cid >> 10;
    int sub  = cid & 1023;
    int row  = sub >> 4;              // 0..63
    int c8   = sub & 15;
    const float* src = fb + (size_t)((tile ? tj : ti) + row) * DD + c8 * 8;
    float4 u = *(const float4*)src;
    float4 v = *(const float4*)(src + 4);
    if (diag && tile == 0)
      regsum += u.x*u.x + u.y*u.y + u.z*u.z + u.w*u.w
              + v.x*v.x + v.y*v.y + v.z*v.z + v.w*v.w;
    bf16_t* dst = (tile ? lsB : lsA) + row * PITCH + c8 * 8;
    dst[0] = (bf16_t)u.x; dst[1] = (bf16_t)u.y; dst[2] = (bf16_t)u.z; dst[3] = (bf16_t)u.w;
    dst[4] = (bf16_t)v.x; dst[5] = (bf16_t)v.y; dst[6] = (bf16_t)v.z; dst[7] = (bf16_t)v.w;
  }
  __syncthreads();

  // ---- row norms from bf16 data (consistent with MFMA dot). 4 threads/row. ----
  {
    int row = t >> 2;                 // 0..127 (A rows then B rows)
    int q   = t & 3;
    const bf16_t* src = (row < BT ? lsA + row * PITCH : lsB + (row - BT) * PITCH)
                        + q * 32;
    float s = 0.f;
    #pragma unroll
    for (int c = 0; c < 4; ++c) {
      bf16x8 ch = *(const bf16x8*)(src + c * 8);
      #pragma unroll
      for (int i = 0; i < 8; ++i) { float v = (float)ch[i]; s += v * v; }
    }
    s += __shfl_xor(s, 1);
    s += __shfl_xor(s, 2);
    if (q == 0) { if (row < BT) nrmA[row] = s; else nrmB[row - BT] = s; }
  }
  // no barrier needed here: nrm consumed only after the post-MFMA barrier

  // ---- MFMA: wave w -> row-frag rf = w>>1 (16 rows), col half h = w&1 ----
  const int lane = t & 63;
  const int wave = t >> 6;
  const int lrow = lane & 15;
  const int quad = lane >> 4;
  const int rf = wave >> 1;
  const int h  = wave & 1;

  f32x4 acc[2];
  acc[0] = (f32x4){0.f,0.f,0.f,0.f};
  acc[1] = (f32x4){0.f,0.f,0.f,0.f};
  #pragma unroll
  for (int k0 = 0; k0 < DD; k0 += 32) {
    const int kc = k0 + quad * 8;
    bf16x8 aF = *(const bf16x8*)&lsA[(rf * 16 + lrow) * PITCH + kc];
    #pragma unroll
    for (int c = 0; c < 2; ++c) {
      bf16x8 bF = *(const bf16x8*)&lsB[((h * 2 + c) * 16 + lrow) * PITCH + kc];
      acc[c] = __builtin_amdgcn_mfma_f32_16x16x32_bf16(aF, bF, acc[c], 0, 0, 0);
    }
  }
  __syncthreads();   // tiles + nrm writes all settled; safe to overlay sq on lsA

  // ---- sq = ||fi||^2 + ||fj||^2 - 2<fi,fj> into LDS (frag-layout write) ----
  {
    const int rbase = rf * 16 + quad * 4;
    #pragma unroll
    for (int c = 0; c < 2; ++c) {
      const int ctile = (h * 2 + c) * 16 + lrow;
      const float ncol = nrmB[ctile];
      #pragma unroll
      for (int r = 0; r < 4; ++r)
        sqb[(rbase + r) * SQP + ctile] =
            fmaxf(nrmA[rbase + r] + ncol - 2.f * acc[c][r], 0.f);
    }
  }
  __syncthreads();

  // ---- phase 2: coalesced sweep, all 4 global float4 loads in flight ----
  float bsum = 0.f, poss = 0.f, posc = 0.f, negs = 0.f, negc = 0.f;
  const size_t base = (size_t)b * NN * NN;
  const int c4 = t & 15, r0 = t >> 4;      // 16 float4-cols, 32 row-slots (x2 rows)
  const int gcol0 = tj + c4 * 4;
  const float* lp = logits + base + (size_t)(ti + r0) * NN + gcol0;
  const float* ap = adj    + base + (size_t)(ti + r0) * NN + gcol0;
  float4 L0 = *(const float4*)lp;
  float4 A0 = *(const float4*)ap;
  float4 L1 = *(const float4*)(lp + (size_t)32 * NN);
  float4 A1 = *(const float4*)(ap + (size_t)32 * NN);
  float4 s0 = *(const float4*)&sqb[r0 * SQP + c4 * 4];
  float4 s1 = *(const float4*)&sqb[(r0 + 32) * SQP + c4 * 4];
  {
    int grow = ti + r0;
    loss_elem(L0.x, A0.x, s0.x, grow, gcol0 + 0, bsum, poss, posc, negs, negc);
    loss_elem(L0.y, A0.y, s0.y, grow, gcol0 + 1, bsum, poss, posc, negs, negc);
    loss_elem(L0.z, A0.z, s0.z, grow, gcol0 + 2, bsum, poss, posc, negs, negc);
    loss_elem(L0.w, A0.w, s0.w, grow, gcol0 + 3, bsum, poss, posc, negs, negc);
    grow += 32;
    loss_elem(L1.x, A1.x, s1.x, grow, gcol0 + 0, bsum, poss, posc, negs, negc);
    loss_elem(L1.y, A1.y, s1.y, grow, gcol0 + 1, bsum, poss, posc, negs, negc);
    loss_elem(L1.z, A1.z, s1.z, grow, gcol0 + 2, bsum, poss, posc, negs, negc);
    loss_elem(L1.w, A1.w, s1.w, grow, gcol0 + 3, bsum, poss, posc, negs, negc);
  }

  // ---- block reduction (8 values) + per-batch atomics ----
  #pragma unroll
  for (int o = 32; o; o >>= 1) {
    bsum     += __shfl_xor(bsum, o);
    poss     += __shfl_xor(poss, o);
    posc     += __shfl_xor(posc, o);
    negs     += __shfl_xor(negs, o);
    negc     += __shfl_xor(negc, o);
    regsum   += __shfl_xor(regsum, o);
    coordsum += __shfl_xor(coordsum, o);
    cntsum   += __shfl_xor(cntsum, o);
  }
  if (lane == 0) {
    red[wave][0] = bsum;   red[wave][1] = poss;     red[wave][2] = posc;
    red[wave][3] = negs;   red[wave][4] = negc;     red[wave][5] = regsum;
    red[wave][6] = coordsum; red[wave][7] = cntsum;
  }
  __syncthreads();
  if (t == 0) {
    float s0_=0.f,s1_=0.f,s2_=0.f,s3_=0.f,s4_=0.f,s5_=0.f,s6_=0.f,s7_=0.f;
    for (int w = 0; w < 8; ++w) {
      s0_ += red[w][0]; s1_ += red[w][1]; s2_ += red[w][2]; s3_ += red[w][3];
      s4_ += red[w][4]; s5_ += red[w][5]; s6_ += red[w][6]; s7_ += red[w][7];
    }
    atomicAdd(&ws[3], s0_);
    atomicAdd(&ws[4 + b], s1_);
    atomicAdd(&ws[20 + b], s2_);
    atomicAdd(&ws[36 + b], s3_);
    atomicAdd(&ws[52 + b], s4_);
    if (diag) atomicAdd(&ws[1], s5_);
    if (special) {
      atomicAdd(&ws[0], s6_);
      float d = fabsf(pcount[b] - s7_);
      float term = (d < 1.f) ? 0.5f * d * d : d - 0.5f;
      atomicAdd(&ws[2], term);
    }
    // ---- ticket: last block finalizes ----
    __threadfence();
    unsigned old = atomicAdd((unsigned*)(ws + 68), 1u);
    if (old == NBLK - 1) {
      __threadfence();
      float v[68];
      for (int i = 0; i < 68; ++i)
        v[i] = __hip_atomic_load(&ws[i], __ATOMIC_RELAXED, __HIP_MEMORY_SCOPE_AGENT);
      float coord = v[0] / 32768.f;
      float reg   = v[1] / 2097152.f;
      float cntl  = v[2] / 16.f;
      float edge  = v[3] / 16777216.f;
      float contra = 0.f;
      for (int bb = 0; bb < 16; ++bb) {
        float p = v[4 + bb]  / fmaxf(v[20 + bb], 1.f);
        float n = v[36 + bb] / fmaxf(v[52 + bb], 1.f);
        contra += p + n;
      }
      contra *= (1.f / 16.f);
      float total = coord + 2.f*edge + 0.1f*cntl + 0.001f*reg + 0.1f*contra;
      out[0] = total; out[1] = coord; out[2] = edge;
      out[3] = cntl;  out[4] = reg;   out[5] = contra;
    }
  }
}

extern "C" void kernel_launch(void* const* d_in, const int* in_sizes, int n_in,
                              void* d_out, int out_size, void* d_ws, size_t ws_size,
                              hipStream_t stream) {
  (void)in_sizes; (void)n_in; (void)out_size; (void)ws_size;
  const float* pcoord = (const float*)d_in[0];
  const float* pts    = (const float*)d_in[1];
  const float* logits = (const float*)d_in[2];
  const float* adj    = (const float*)d_in[3];
  const float* masks  = (const float*)d_in[4];
  const float* pcount = (const float*)d_in[5];
  const float* nf     = (const float*)d_in[6];
  float* ws  = (float*)d_ws;
  float* out = (float*)d_out;

  hipMemsetAsync(ws, 0, 69 * sizeof(float), stream);
  fused_all<<<NBLK, 512, 0, stream>>>(logits, adj, nf, pcoord, pts, masks,
                                      pcount, ws, out);
}

// Round 5
// 237.435 us; speedup vs baseline: 1.5513x; 1.5513x over previous
//
#include <hip/hip_runtime.h>
#include <hip/hip_bf16.h>

#define NN    1024
#define DD    128
#define TILE  128
#define PITCH 136    // bf16 elems per LDS tile row (128 + 8 pad, 16B-aligned rows)
#define SQP   132    // f32 elems per LDS sq row (128 + 4 pad)
#define NBLK  1024   // 16 batches x 8x8 tiles of 128x128

typedef __bf16 bf16_t;
typedef bf16_t bf16x8 __attribute__((ext_vector_type(8)));
typedef float  f32x4  __attribute__((ext_vector_type(4)));

// ws layout (floats):
// [0] coord_sum  [1] reg_sum  [2] count_loss_sum  [3] bce_sum
// [4+b] pos_sum  [20+b] pos_cnt  [36+b] neg_sum  [52+b] neg_cnt
// [68] ticket counter (as unsigned)  -> 69 floats, memset 276 B

__device__ __forceinline__ void loss_elem(float l, float a, float s, int grow, int gcol,
    float& bsum, float& poss, float& posc, float& negs, float& negc) {
  bsum += fmaxf(l, 0.f) - l * a + __logf(1.f + __expf(-fabsf(l)));
  if (a > 0.5f) {
    poss += s; posc += 1.f;
  } else if (grow != gcol) {
    negc += 1.f;
    if (s < 1.f) {                      // essentially never for random 128-d features
      float d = sqrtf(fmaxf(s, 1e-12f));
      float h = 1.f - d;
      negs += h * h;
    }
  }
}

__global__ __launch_bounds__(512, 4) void fused_all(
    const float* __restrict__ logits, const float* __restrict__ adj,
    const float* __restrict__ feat,   const float* __restrict__ pcoord,
    const float* __restrict__ pts,    const float* __restrict__ masks,
    const float* __restrict__ pcount, float* __restrict__ ws,
    float* __restrict__ out) {
  // tiles (2*128*136*2 = 69632 B); sq buffer (128*132*4 = 67584 B) overlays post-MFMA
  __shared__ __align__(16) char smem[2 * TILE * PITCH * sizeof(bf16_t)];
  bf16_t* lsA = (bf16_t*)smem;
  bf16_t* lsB = (bf16_t*)(smem + TILE * PITCH * sizeof(bf16_t));
  float*  sqb = (float*)smem;
  __shared__ float nrmA[TILE], nrmB[TILE];
  __shared__ float red[8][8];

  const int bx  = blockIdx.x;
  const int b   = bx >> 6;            // 64 tiles per batch
  const int tid = bx & 63;
  const int ti  = (tid >> 3) << 7;    // tile row base
  const int tj  = (tid & 7)  << 7;    // tile col base
  const bool diag    = ((tid >> 3) == (tid & 7));  // 8/batch: partition rows for reg
  const bool special = (tid == 0);                 // 1/batch: coord/mask/count

  const int t = threadIdx.x;          // 0..511, 8 waves
  const float* fb = feat + (size_t)b * NN * DD;

  // ---- phase-2 addressing + EARLY PREFETCH of first 4 (L,A) float4 pairs ----
  // These loads are independent of everything below; they complete during the
  // staging/norm/MFMA section so phase 2 starts with data already in registers.
  const int c4 = t & 31, r0 = t >> 5;     // 32 float4-cols x 16 rows per step
  const int gcol0 = tj + c4 * 4;
  const size_t base = (size_t)b * NN * NN;
  const float* lp = logits + base + (size_t)(ti + r0) * NN + gcol0;
  const float* ap = adj    + base + (size_t)(ti + r0) * NN + gcol0;
  float4 Lb[4], Ab[4];
  #pragma unroll
  for (int i = 0; i < 4; ++i) {
    Lb[i] = *(const float4*)(lp + (size_t)i * 16 * NN);
    Ab[i] = *(const float4*)(ap + (size_t)i * 16 * NN);
  }

  // ---- per-batch extras on special blocks ----
  float coordsum = 0.f, cntsum = 0.f;
  if (special) {
    const float4* a4 = (const float4*)(pcoord + (size_t)b * NN * 2);
    const float4* b4 = (const float4*)(pts    + (size_t)b * NN * 2);
    float4 ac = a4[t], bc = b4[t];    // 512 float4 = the batch's 1024x2 coords
    float dx = ac.x-bc.x, dy = ac.y-bc.y, dz = ac.z-bc.z, dw = ac.w-bc.w;
    coordsum = dx*dx + dy*dy + dz*dz + dw*dw;
    const float* m = masks + b * NN;
    cntsum = m[t] + m[t + 512];
  }

  // ---- stage A rows [ti,ti+128) and B rows [tj,tj+128) as bf16 into LDS ----
  // Diagonal blocks accumulate fp32 sum(nf^2) from the A tile (the 8 diagonal
  // blocks' A bands partition the batch's 1024 rows -> counted exactly once).
  float regsum = 0.f;
  #pragma unroll
  for (int it = 0; it < 8; ++it) {
    int cid  = it * 512 + t;          // 0..4095 chunks of 8 floats
    int tile = cid >> 11;
    int sub  = cid & 2047;
    int row  = sub >> 4;              // 0..127
    int c8   = sub & 15;
    const float* src = fb + (size_t)((tile ? tj : ti) + row) * DD + c8 * 8;
    float4 u = *(const float4*)src;
    float4 v = *(const float4*)(src + 4);
    if (diag && tile == 0)
      regsum += u.x*u.x + u.y*u.y + u.z*u.z + u.w*u.w
              + v.x*v.x + v.y*v.y + v.z*v.z + v.w*v.w;
    bf16_t* dst = (tile ? lsB : lsA) + row * PITCH + c8 * 8;
    dst[0] = (bf16_t)u.x; dst[1] = (bf16_t)u.y; dst[2] = (bf16_t)u.z; dst[3] = (bf16_t)u.w;
    dst[4] = (bf16_t)v.x; dst[5] = (bf16_t)v.y; dst[6] = (bf16_t)v.z; dst[7] = (bf16_t)v.w;
  }
  __syncthreads();

  // ---- row norms from bf16 data (consistent with MFMA dot). 2 threads/row. ----
  {
    int row  = t >> 1;                // 0..255 (A rows then B rows)
    int half = t & 1;
    const bf16_t* src = (row < TILE ? lsA + row * PITCH : lsB + (row - TILE) * PITCH)
                        + half * 64;
    float s = 0.f;
    #pragma unroll
    for (int c = 0; c < 8; ++c) {
      bf16x8 ch = *(const bf16x8*)(src + c * 8);
      #pragma unroll
      for (int i = 0; i < 8; ++i) { float v = (float)ch[i]; s += v * v; }
    }
    s += __shfl_xor(s, 1);
    if (half == 0) { if (row < TILE) nrmA[row] = s; else nrmB[row - TILE] = s; }
  }
  // nrm consumed only after the post-MFMA barrier; no barrier needed here

  // ---- MFMA Gram: wave w computes rows [w*16, w*16+16) x all 128 cols ----
  const int lane = t & 63;
  const int wave = t >> 6;            // 0..7
  const int lrow = lane & 15;
  const int quad = lane >> 4;

  f32x4 acc[8];
  #pragma unroll
  for (int fc = 0; fc < 8; ++fc) acc[fc] = (f32x4){0.f, 0.f, 0.f, 0.f};

  #pragma unroll
  for (int k0 = 0; k0 < DD; k0 += 32) {
    const int kc = k0 + quad * 8;
    bf16x8 aF = *(const bf16x8*)&lsA[(wave * 16 + lrow) * PITCH + kc];
    bf16x8 bF[8];
    #pragma unroll
    for (int fc = 0; fc < 8; ++fc)
      bF[fc] = *(const bf16x8*)&lsB[(fc * 16 + lrow) * PITCH + kc];
    #pragma unroll
    for (int fc = 0; fc < 8; ++fc)
      acc[fc] = __builtin_amdgcn_mfma_f32_16x16x32_bf16(aF, bF[fc], acc[fc], 0, 0, 0);
  }
  __syncthreads();   // tiles + nrm writes settled; safe to overlay sq

  // ---- sq = ||fi||^2 + ||fj||^2 - 2<fi,fj> into LDS (frag-layout write) ----
  {
    const int rbase = wave * 16 + quad * 4;
    #pragma unroll
    for (int fc = 0; fc < 8; ++fc) {
      const int ctile = fc * 16 + lrow;
      const float ncol = nrmB[ctile];
      #pragma unroll
      for (int r = 0; r < 4; ++r) {
        const int rtile = rbase + r;
        sqb[rtile * SQP + ctile] = fmaxf(nrmA[rtile] + ncol - 2.f * acc[fc][r], 0.f);
      }
    }
  }
  __syncthreads();

  // ---- phase 2: coalesced sweep, depth-4 software pipeline (4 pairs in flight) ----
  float bsum = 0.f, poss = 0.f, posc = 0.f, negs = 0.f, negc = 0.f;
  #pragma unroll
  for (int it = 0; it < 8; ++it) {
    float4 L = Lb[it & 3], A = Ab[it & 3];
    if (it < 4) {     // issue load for iteration it+4 before consuming it
      Lb[it & 3] = *(const float4*)(lp + (size_t)(it + 4) * 16 * NN);
      Ab[it & 3] = *(const float4*)(ap + (size_t)(it + 4) * 16 * NN);
    }
    const int row  = it * 16 + r0;
    const int grow = ti + row;
    float4 s = *(const float4*)&sqb[row * SQP + c4 * 4];
    loss_elem(L.x, A.x, s.x, grow, gcol0 + 0, bsum, poss, posc, negs, negc);
    loss_elem(L.y, A.y, s.y, grow, gcol0 + 1, bsum, poss, posc, negs, negc);
    loss_elem(L.z, A.z, s.z, grow, gcol0 + 2, bsum, poss, posc, negs, negc);
    loss_elem(L.w, A.w, s.w, grow, gcol0 + 3, bsum, poss, posc, negs, negc);
  }

  // ---- block reduction (8 values) + per-batch atomics ----
  #pragma unroll
  for (int o = 32; o; o >>= 1) {
    bsum     += __shfl_xor(bsum, o);
    poss     += __shfl_xor(poss, o);
    posc     += __shfl_xor(posc, o);
    negs     += __shfl_xor(negs, o);
    negc     += __shfl_xor(negc, o);
    regsum   += __shfl_xor(regsum, o);
    coordsum += __shfl_xor(coordsum, o);
    cntsum   += __shfl_xor(cntsum, o);
  }
  if (lane == 0) {
    red[wave][0] = bsum;     red[wave][1] = poss;   red[wave][2] = posc;
    red[wave][3] = negs;     red[wave][4] = negc;   red[wave][5] = regsum;
    red[wave][6] = coordsum; red[wave][7] = cntsum;
  }
  __syncthreads();
  if (t == 0) {
    float s0=0.f,s1=0.f,s2=0.f,s3=0.f,s4=0.f,s5=0.f,s6=0.f,s7=0.f;
    for (int w = 0; w < 8; ++w) {
      s0 += red[w][0]; s1 += red[w][1]; s2 += red[w][2]; s3 += red[w][3];
      s4 += red[w][4]; s5 += red[w][5]; s6 += red[w][6]; s7 += red[w][7];
    }
    atomicAdd(&ws[3], s0);
    atomicAdd(&ws[4 + b], s1);
    atomicAdd(&ws[20 + b], s2);
    atomicAdd(&ws[36 + b], s3);
    atomicAdd(&ws[52 + b], s4);
    if (diag) atomicAdd(&ws[1], s5);
    if (special) {
      atomicAdd(&ws[0], s6);
      float d = fabsf(pcount[b] - s7);
      float term = (d < 1.f) ? 0.5f * d * d : d - 0.5f;
      atomicAdd(&ws[2], term);
    }
    // ---- ticket: last block finalizes ----
    __threadfence();
    unsigned old = atomicAdd((unsigned*)(ws + 68), 1u);
    if (old == NBLK - 1) {
      __threadfence();
      float v[68];
      for (int i = 0; i < 68; ++i)
        v[i] = __hip_atomic_load(&ws[i], __ATOMIC_RELAXED, __HIP_MEMORY_SCOPE_AGENT);
      float coord = v[0] / 32768.f;
      float reg   = v[1] / 2097152.f;
      float cntl  = v[2] / 16.f;
      float edge  = v[3] / 16777216.f;
      float contra = 0.f;
      for (int bb = 0; bb < 16; ++bb) {
        float p = v[4 + bb]  / fmaxf(v[20 + bb], 1.f);
        float n = v[36 + bb] / fmaxf(v[52 + bb], 1.f);
        contra += p + n;
      }
      contra *= (1.f / 16.f);
      float total = coord + 2.f*edge + 0.1f*cntl + 0.001f*reg + 0.1f*contra;
      out[0] = total; out[1] = coord; out[2] = edge;
      out[3] = cntl;  out[4] = reg;   out[5] = contra;
    }
  }
}

extern "C" void kernel_launch(void* const* d_in, const int* in_sizes, int n_in,
                              void* d_out, int out_size, void* d_ws, size_t ws_size,
                              hipStream_t stream) {
  (void)in_sizes; (void)n_in; (void)out_size; (void)ws_size;
  const float* pcoord = (const float*)d_in[0];
  const float* pts    = (const float*)d_in[1];
  const float* logits = (const float*)d_in[2];
  const float* adj    = (const float*)d_in[3];
  const float* masks  = (const float*)d_in[4];
  const float* pcount = (const float*)d_in[5];
  const float* nf     = (const float*)d_in[6];
  float* ws  = (float*)d_ws;
  float* out = (float*)d_out;

  hipMemsetAsync(ws, 0, 69 * sizeof(float), stream);
  fused_all<<<NBLK, 512, 0, stream>>>(logits, adj, nf, pcoord, pts, masks,
                                      pcount, ws, out);
}

// Round 6
// 212.301 us; speedup vs baseline: 1.7350x; 1.1184x over previous
//
#include <hip/hip_runtime.h>
#include <hip/hip_bf16.h>

#define NN    1024
#define DD    128
#define AR    64     // A-tile rows (output rows per block)
#define BR    128    // B-tile rows (output cols per block)
#define PITCH 136    // bf16 elems per LDS tile row (128 + 8 pad, 16B-aligned rows)
#define SQP   132    // f32 elems per LDS sq row (128 + 4 pad)
#define NBLK  2048   // 16 batches x 16 row-bands x 8 col-tiles

typedef __bf16 bf16_t;
typedef bf16_t bf16x8 __attribute__((ext_vector_type(8)));
typedef float  f32x4  __attribute__((ext_vector_type(4)));

// ws layout (floats):
// [0] coord_sum  [1] reg_sum  [2] count_loss_sum  [3] bce_sum
// [4+b] pos_sum  [20+b] pos_cnt  [36+b] neg_sum  [52+b] neg_cnt  -> 68 floats

__global__ __launch_bounds__(256) void small_losses(
    const float* __restrict__ pcoord, const float* __restrict__ pts,
    const float* __restrict__ masks,  const float* __restrict__ pcount,
    float* __restrict__ ws) {
  __shared__ float sh[4][2];
  float coord = 0.f, cnt = 0.f;

  const int gt = blockIdx.x * 256 + threadIdx.x;
  const int stride = 16 * 256;

  const float4* a4 = (const float4*)pcoord;
  const float4* b4 = (const float4*)pts;
  for (int i = gt; i < 8192; i += stride) {
    float4 a = a4[i], b = b4[i];
    float dx = a.x-b.x, dy = a.y-b.y, dz = a.z-b.z, dw = a.w-b.w;
    coord += dx*dx + dy*dy + dz*dz + dw*dw;
  }
  const float* m = masks + blockIdx.x * NN;
  for (int i = threadIdx.x; i < NN; i += 256) cnt += m[i];

  const int lane = threadIdx.x & 63, w = threadIdx.x >> 6;
  #pragma unroll
  for (int o = 32; o; o >>= 1) {
    coord += __shfl_xor(coord, o);
    cnt   += __shfl_xor(cnt, o);
  }
  if (lane == 0) { sh[w][0] = coord; sh[w][1] = cnt; }
  __syncthreads();
  if (threadIdx.x == 0) {
    float c = 0.f, n = 0.f;
    for (int i = 0; i < 4; ++i) { c += sh[i][0]; n += sh[i][1]; }
    atomicAdd(&ws[0], c);
    float d = fabsf(pcount[blockIdx.x] - n);
    float term = (d < 1.f) ? 0.5f * d * d : d - 0.5f;
    atomicAdd(&ws[2], term);
  }
}

__device__ __forceinline__ void loss_elem(float l, float a, float s, int grow, int gcol,
    float& bsum, float& poss, float& posc, float& negs, float& negc) {
  bsum += fmaxf(l, 0.f) - l * a + __logf(1.f + __expf(-fabsf(l)));
  if (a > 0.5f) {
    poss += s; posc += 1.f;
  } else if (grow != gcol) {
    negc += 1.f;
    if (s < 1.f) {                      // essentially never for random 128-d features
      float d = sqrtf(fmaxf(s, 1e-12f));
      float h = 1.f - d;
      negs += h * h;
    }
  }
}

// 64x128 output tile per block. LDS: lsA 64 rows + lsB 128 rows (52224 B) +
// nrm/red (~1 KB) = 53248 B -> 3 blocks/CU (24 waves). launch_bounds(512,6)
// caps VGPR at ~84 so registers don't drop us back to 2 blocks.
__global__ __launch_bounds__(512, 6) void fused_gram_bce(
    const float* __restrict__ logits, const float* __restrict__ adj,
    const float* __restrict__ feat, float* __restrict__ ws) {
  __shared__ __align__(16) char smem[(AR + BR) * PITCH * sizeof(bf16_t)];
  bf16_t* lsA = (bf16_t*)smem;
  bf16_t* lsB = (bf16_t*)(smem + AR * PITCH * sizeof(bf16_t));
  float*  sqb = (float*)smem;   // 64*132*4 = 33792 B overlay post-MFMA
  __shared__ float nrmA[AR], nrmB[BR];
  __shared__ float red[8][6];

  const int bx  = blockIdx.x;
  const int b   = bx >> 7;            // 128 tiles per batch
  const int tid = bx & 127;
  const int ti  = (tid >> 3) << 6;    // row-band base (16 bands of 64)
  const int tj  = (tid & 7)  << 7;    // col-tile base (8 tiles of 128)
  const bool regblk = ((tid & 7) == 0);  // col-tile 0: A bands partition rows

  const int t = threadIdx.x;          // 0..511, 8 waves
  const float* fb = feat + (size_t)b * NN * DD;

  // ---- stage A rows [ti,ti+64) and B rows [tj,tj+128) as bf16 into LDS ----
  float regsum = 0.f;
  #pragma unroll
  for (int it = 0; it < 6; ++it) {
    int cid  = it * 512 + t;          // 0..3071 chunks of 8 floats (192 rows x 16)
    int row  = cid >> 4;              // 0..191
    int c8   = cid & 15;
    const bool isA = row < AR;
    const int grow = isA ? (ti + row) : (tj + row - AR);
    const float* src = fb + (size_t)grow * DD + c8 * 8;
    float4 u = *(const float4*)src;
    float4 v = *(const float4*)(src + 4);
    if (regblk && isA)
      regsum += u.x*u.x + u.y*u.y + u.z*u.z + u.w*u.w
              + v.x*v.x + v.y*v.y + v.z*v.z + v.w*v.w;
    bf16_t* dst = (isA ? lsA + row * PITCH : lsB + (row - AR) * PITCH) + c8 * 8;
    dst[0] = (bf16_t)u.x; dst[1] = (bf16_t)u.y; dst[2] = (bf16_t)u.z; dst[3] = (bf16_t)u.w;
    dst[4] = (bf16_t)v.x; dst[5] = (bf16_t)v.y; dst[6] = (bf16_t)v.z; dst[7] = (bf16_t)v.w;
  }
  __syncthreads();

  // ---- row norms from bf16 data (consistent with MFMA dot). 2 threads/row. ----
  if (t < 384) {
    int row  = t >> 1;                // 0..191 (A rows then B rows)
    int half = t & 1;
    const bf16_t* src = (row < AR ? lsA + row * PITCH : lsB + (row - AR) * PITCH)
                        + half * 64;
    float s = 0.f;
    #pragma unroll
    for (int c = 0; c < 8; ++c) {
      bf16x8 ch = *(const bf16x8*)(src + c * 8);
      #pragma unroll
      for (int i = 0; i < 8; ++i) { float v = (float)ch[i]; s += v * v; }
    }
    s += __shfl_xor(s, 1);
    if (half == 0) { if (row < AR) nrmA[row] = s; else nrmB[row - AR] = s; }
  }
  // nrm consumed only after the post-MFMA barrier

  // ---- MFMA: wave w -> rows [(w>>1)*16,+16), col half h=w&1 (64 cols) ----
  const int lane = t & 63;
  const int wave = t >> 6;
  const int lrow = lane & 15;
  const int quad = lane >> 4;
  const int rf = wave >> 1;           // 0..3
  const int h  = wave & 1;

  f32x4 acc[4];
  #pragma unroll
  for (int fc = 0; fc < 4; ++fc) acc[fc] = (f32x4){0.f, 0.f, 0.f, 0.f};

  #pragma unroll
  for (int k0 = 0; k0 < DD; k0 += 32) {
    const int kc = k0 + quad * 8;
    bf16x8 aF = *(const bf16x8*)&lsA[(rf * 16 + lrow) * PITCH + kc];
    #pragma unroll
    for (int fc = 0; fc < 4; ++fc) {
      bf16x8 bF = *(const bf16x8*)&lsB[((h * 4 + fc) * 16 + lrow) * PITCH + kc];
      acc[fc] = __builtin_amdgcn_mfma_f32_16x16x32_bf16(aF, bF, acc[fc], 0, 0, 0);
    }
  }

  // ---- phase-2 prefetch (registers are free here; hides behind 2 barriers) ----
  const int c4 = t & 31, r0 = t >> 5;      // 32 float4-cols x 16 rows per step
  const int gcol0 = tj + c4 * 4;
  const size_t base = (size_t)b * NN * NN;
  const float* lp = logits + base + (size_t)(ti + r0) * NN + gcol0;
  const float* ap = adj    + base + (size_t)(ti + r0) * NN + gcol0;
  float4 L0 = *(const float4*)lp;
  float4 A0 = *(const float4*)ap;

  __syncthreads();   // tiles + nrm writes settled; safe to overlay sq

  // ---- sq = ||fi||^2 + ||fj||^2 - 2<fi,fj> into LDS (frag-layout write) ----
  {
    const int rbase = rf * 16 + quad * 4;
    #pragma unroll
    for (int fc = 0; fc < 4; ++fc) {
      const int ctile = (h * 4 + fc) * 16 + lrow;
      const float ncol = nrmB[ctile];
      #pragma unroll
      for (int r = 0; r < 4; ++r) {
        const int rtile = rbase + r;
        sqb[rtile * SQP + ctile] = fmaxf(nrmA[rtile] + ncol - 2.f * acc[fc][r], 0.f);
      }
    }
  }
  __syncthreads();

  // ---- phase 2: coalesced sweep, depth-2 pipeline, 4 iterations ----
  float bsum = 0.f, poss = 0.f, posc = 0.f, negs = 0.f, negc = 0.f;
  #pragma unroll
  for (int it = 0; it < 4; ++it) {
    float4 L = L0, A = A0;
    if (it < 3) {
      L0 = *(const float4*)(lp + (size_t)(it + 1) * 16 * NN);
      A0 = *(const float4*)(ap + (size_t)(it + 1) * 16 * NN);
    }
    const int row  = it * 16 + r0;
    const int grow = ti + row;
    float4 s = *(const float4*)&sqb[row * SQP + c4 * 4];
    loss_elem(L.x, A.x, s.x, grow, gcol0 + 0, bsum, poss, posc, negs, negc);
    loss_elem(L.y, A.y, s.y, grow, gcol0 + 1, bsum, poss, posc, negs, negc);
    loss_elem(L.z, A.z, s.z, grow, gcol0 + 2, bsum, poss, posc, negs, negc);
    loss_elem(L.w, A.w, s.w, grow, gcol0 + 3, bsum, poss, posc, negs, negc);
  }

  // ---- block reduction (6 values) + per-batch atomics ----
  #pragma unroll
  for (int o = 32; o; o >>= 1) {
    bsum   += __shfl_xor(bsum, o);
    poss   += __shfl_xor(poss, o);
    posc   += __shfl_xor(posc, o);
    negs   += __shfl_xor(negs, o);
    negc   += __shfl_xor(negc, o);
    regsum += __shfl_xor(regsum, o);
  }
  if (lane == 0) {
    red[wave][0] = bsum; red[wave][1] = poss; red[wave][2] = posc;
    red[wave][3] = negs; red[wave][4] = negc; red[wave][5] = regsum;
  }
  __syncthreads();
  if (t == 0) {
    float s0=0.f,s1=0.f,s2=0.f,s3=0.f,s4=0.f,s5=0.f;
    for (int w = 0; w < 8; ++w) {
      s0 += red[w][0]; s1 += red[w][1]; s2 += red[w][2];
      s3 += red[w][3]; s4 += red[w][4]; s5 += red[w][5];
    }
    atomicAdd(&ws[3], s0);
    atomicAdd(&ws[4 + b], s1);
    atomicAdd(&ws[20 + b], s2);
    atomicAdd(&ws[36 + b], s3);
    atomicAdd(&ws[52 + b], s4);
    if (regblk) atomicAdd(&ws[1], s5);
  }
}

__global__ void finalize(const float* __restrict__ ws, float* __restrict__ out) {
  if (threadIdx.x != 0 || blockIdx.x != 0) return;
  float coord = ws[0] / 32768.f;
  float reg   = ws[1] / 2097152.f;
  float cntl  = ws[2] / 16.f;
  float edge  = ws[3] / 16777216.f;
  float contra = 0.f;
  for (int b = 0; b < 16; ++b) {
    float p = ws[4 + b]  / fmaxf(ws[20 + b], 1.f);
    float n = ws[36 + b] / fmaxf(ws[52 + b], 1.f);
    contra += p + n;
  }
  contra *= (1.f / 16.f);
  float total = coord + 2.f * edge + 0.1f * cntl + 0.001f * reg + 0.1f * contra;
  out[0] = total; out[1] = coord; out[2] = edge;
  out[3] = cntl;  out[4] = reg;   out[5] = contra;
}

extern "C" void kernel_launch(void* const* d_in, const int* in_sizes, int n_in,
                              void* d_out, int out_size, void* d_ws, size_t ws_size,
                              hipStream_t stream) {
  (void)in_sizes; (void)n_in; (void)out_size; (void)ws_size;
  const float* pcoord = (const float*)d_in[0];
  const float* pts    = (const float*)d_in[1];
  const float* logits = (const float*)d_in[2];
  const float* adj    = (const float*)d_in[3];
  const float* masks  = (const float*)d_in[4];
  const float* pcount = (const float*)d_in[5];
  const float* nf     = (const float*)d_in[6];
  float* ws  = (float*)d_ws;
  float* out = (float*)d_out;

  hipMemsetAsync(ws, 0, 68 * sizeof(float), stream);
  small_losses<<<16, 256, 0, stream>>>(pcoord, pts, masks, pcount, ws);
  fused_gram_bce<<<NBLK, 512, 0, stream>>>(logits, adj, nf, ws);
  finalize<<<1, 64, 0, stream>>>(ws, out);
}

// Round 7
// 199.814 us; speedup vs baseline: 1.8434x; 1.0625x over previous
//
#include <hip/hip_runtime.h>
#include <hip/hip_bf16.h>

#define NN    1024
#define DD    128
#define TILE  128
#define PITCH 136   // bf16 elems per LDS tile row: 128 + 8 pad
#define SQP   132   // f32 elems per LDS sq row: 128 + 4 pad
#define NBLK  1024

typedef __bf16 bf16_t;
typedef bf16_t bf16x8 __attribute__((ext_vector_type(8)));
typedef float  f32x4  __attribute__((ext_vector_type(4)));

// ws layout (floats):
// [0] coord_sum  [1] reg_sum  [2] count_loss_sum  [3] bce_sum
// [4+b] pos_sum  [20+b] pos_cnt  [36+b] neg_sum  [52+b] neg_cnt  -> 68 floats

__global__ __launch_bounds__(256) void small_losses(
    const float* __restrict__ pcoord, const float* __restrict__ pts,
    const float* __restrict__ masks,  const float* __restrict__ pcount,
    float* __restrict__ ws) {
  __shared__ float sh[4][2];
  float coord = 0.f, cnt = 0.f;

  const int gt = blockIdx.x * 256 + threadIdx.x;
  const int stride = 16 * 256;

  const float4* a4 = (const float4*)pcoord;
  const float4* b4 = (const float4*)pts;
  for (int i = gt; i < 8192; i += stride) {
    float4 a = a4[i], b = b4[i];
    float dx = a.x-b.x, dy = a.y-b.y, dz = a.z-b.z, dw = a.w-b.w;
    coord += dx*dx + dy*dy + dz*dz + dw*dw;
  }
  const float* m = masks + blockIdx.x * NN;
  for (int i = threadIdx.x; i < NN; i += 256) cnt += m[i];

  const int lane = threadIdx.x & 63, w = threadIdx.x >> 6;
  #pragma unroll
  for (int o = 32; o; o >>= 1) {
    coord += __shfl_xor(coord, o);
    cnt   += __shfl_xor(cnt, o);
  }
  if (lane == 0) { sh[w][0] = coord; sh[w][1] = cnt; }
  __syncthreads();
  if (threadIdx.x == 0) {
    float c = 0.f, n = 0.f;
    for (int i = 0; i < 4; ++i) { c += sh[i][0]; n += sh[i][1]; }
    atomicAdd(&ws[0], c);
    float d = fabsf(pcount[blockIdx.x] - n);
    float term = (d < 1.f) ? 0.5f * d * d : d - 0.5f;
    atomicAdd(&ws[2], term);
  }
}

__device__ __forceinline__ void loss_elem(float l, float a, float s, int grow, int gcol,
    float& bsum, float& poss, float& posc, float& negs, float& negc) {
  bsum += fmaxf(l, 0.f) - l * a + __logf(1.f + __expf(-fabsf(l)));
  if (a > 0.5f) {
    poss += s; posc += 1.f;
  } else if (grow != gcol) {
    negc += 1.f;
    if (s < 1.f) {                      // essentially never for random 128-d features
      float d = sqrtf(fmaxf(s, 1e-12f));
      float h = 1.f - d;
      negs += h * h;
    }
  }
}

__global__ __launch_bounds__(512, 4) void fused_gram_bce(
    const float* __restrict__ logits, const float* __restrict__ adj,
    const float* __restrict__ feat, float* __restrict__ ws) {
  // tiles (2*128*136*2 = 69632 B); sq buffer (128*132*4 = 67584 B) overlays post-MFMA
  __shared__ __align__(16) char smem[2 * TILE * PITCH * sizeof(bf16_t)];
  bf16_t* lsA = (bf16_t*)smem;
  bf16_t* lsB = (bf16_t*)(smem + TILE * PITCH * sizeof(bf16_t));
  float*  sqb = (float*)smem;
  __shared__ float nrmA[TILE], nrmB[TILE];
  __shared__ float red[8][6];

  const int bx  = blockIdx.x;
  const int b   = bx >> 6;            // 64 tiles per batch
  const int tid = bx & 63;
  const int ti  = (tid >> 3) << 7;    // tile row base
  const int tj  = (tid & 7)  << 7;    // tile col base
  const bool diag = ((tid >> 3) == (tid & 7));  // 8/batch: A bands partition rows

  const int t = threadIdx.x;          // 0..511, 8 waves
  const float* fb = feat + (size_t)b * NN * DD;

  // ---- stage A rows [ti,ti+128) and B rows [tj,tj+128) as bf16 into LDS ----
  float regsum = 0.f;
  #pragma unroll
  for (int it = 0; it < 8; ++it) {
    int cid  = it * 512 + t;          // 0..4095 chunks of 8 floats
    int tile = cid >> 11;
    int sub  = cid & 2047;
    int row  = sub >> 4;              // 0..127
    int c8   = sub & 15;
    const float* src = fb + (size_t)((tile ? tj : ti) + row) * DD + c8 * 8;
    float4 u = *(const float4*)src;
    float4 v = *(const float4*)(src + 4);
    if (diag && tile == 0)
      regsum += u.x*u.x + u.y*u.y + u.z*u.z + u.w*u.w
              + v.x*v.x + v.y*v.y + v.z*v.z + v.w*v.w;
    bf16_t* dst = (tile ? lsB : lsA) + row * PITCH + c8 * 8;
    dst[0] = (bf16_t)u.x; dst[1] = (bf16_t)u.y; dst[2] = (bf16_t)u.z; dst[3] = (bf16_t)u.w;
    dst[4] = (bf16_t)v.x; dst[5] = (bf16_t)v.y; dst[6] = (bf16_t)v.z; dst[7] = (bf16_t)v.w;
  }
  __syncthreads();

  // ---- row norms from bf16 data (consistent with MFMA dot). 2 threads/row. ----
  {
    int row  = t >> 1;                // 0..255 (A rows then B rows)
    int half = t & 1;
    const bf16_t* src = (row < TILE ? lsA + row * PITCH : lsB + (row - TILE) * PITCH)
                        + half * 64;
    float s = 0.f;
    #pragma unroll
    for (int c = 0; c < 8; ++c) {
      bf16x8 ch = *(const bf16x8*)(src + c * 8);
      #pragma unroll
      for (int i = 0; i < 8; ++i) { float v = (float)ch[i]; s += v * v; }
    }
    s += __shfl_xor(s, 1);
    if (half == 0) { if (row < TILE) nrmA[row] = s; else nrmB[row - TILE] = s; }
  }
  // nrm consumed only after the post-MFMA barrier

  // ---- MFMA Gram: wave w computes rows [w*16, w*16+16) x all 128 cols ----
  const int lane = t & 63;
  const int wave = t >> 6;            // 0..7
  const int lrow = lane & 15;
  const int quad = lane >> 4;

  f32x4 acc[8];
  #pragma unroll
  for (int fc = 0; fc < 8; ++fc) acc[fc] = (f32x4){0.f, 0.f, 0.f, 0.f};

  #pragma unroll
  for (int k0 = 0; k0 < DD; k0 += 32) {
    const int kc = k0 + quad * 8;
    bf16x8 aF = *(const bf16x8*)&lsA[(wave * 16 + lrow) * PITCH + kc];
    bf16x8 bF[8];
    #pragma unroll
    for (int fc = 0; fc < 8; ++fc)
      bF[fc] = *(const bf16x8*)&lsB[(fc * 16 + lrow) * PITCH + kc];
    #pragma unroll
    for (int fc = 0; fc < 8; ++fc)
      acc[fc] = __builtin_amdgcn_mfma_f32_16x16x32_bf16(aF, bF[fc], acc[fc], 0, 0, 0);
  }

  // ---- issue ALL phase-2 global loads NOW (8 (L,A) float4 pairs in flight).
  // Their ~900-cycle latency overlaps the sq write + 2 barriers + early
  // consume iterations. 64 VGPRs of payload; acc dies right after sq write.
  const int c4 = t & 31, r0 = t >> 5;      // 32 float4-cols x 16 rows per step
  const int gcol0 = tj + c4 * 4;
  const size_t base = (size_t)b * NN * NN;
  const float* lp = logits + base + (size_t)(ti + r0) * NN + gcol0;
  const float* ap = adj    + base + (size_t)(ti + r0) * NN + gcol0;
  float4 Lb[8], Ab[8];
  #pragma unroll
  for (int i = 0; i < 8; ++i) {
    Lb[i] = *(const float4*)(lp + (size_t)i * 16 * NN);
    Ab[i] = *(const float4*)(ap + (size_t)i * 16 * NN);
  }

  __syncthreads();   // tiles + nrm writes settled; safe to overlay sq

  // ---- sq = ||fi||^2 + ||fj||^2 - 2<fi,fj> into LDS (frag-layout write) ----
  {
    const int rbase = wave * 16 + quad * 4;
    #pragma unroll
    for (int fc = 0; fc < 8; ++fc) {
      const int ctile = fc * 16 + lrow;
      const float ncol = nrmB[ctile];
      #pragma unroll
      for (int r = 0; r < 4; ++r) {
        const int rtile = rbase + r;
        sqb[rtile * SQP + ctile] = fmaxf(nrmA[rtile] + ncol - 2.f * acc[fc][r], 0.f);
      }
    }
  }
  __syncthreads();

  // ---- phase 2: consume — no global loads left in the loop ----
  float bsum = 0.f, poss = 0.f, posc = 0.f, negs = 0.f, negc = 0.f;
  #pragma unroll
  for (int it = 0; it < 8; ++it) {
    const int row  = it * 16 + r0;
    const int grow = ti + row;
    float4 L = Lb[it], A = Ab[it];
    float4 s = *(const float4*)&sqb[row * SQP + c4 * 4];
    loss_elem(L.x, A.x, s.x, grow, gcol0 + 0, bsum, poss, posc, negs, negc);
    loss_elem(L.y, A.y, s.y, grow, gcol0 + 1, bsum, poss, posc, negs, negc);
    loss_elem(L.z, A.z, s.z, grow, gcol0 + 2, bsum, poss, posc, negs, negc);
    loss_elem(L.w, A.w, s.w, grow, gcol0 + 3, bsum, poss, posc, negs, negc);
  }

  // ---- block reduction (6 values) + per-batch atomics ----
  #pragma unroll
  for (int o = 32; o; o >>= 1) {
    bsum   += __shfl_xor(bsum, o);
    poss   += __shfl_xor(poss, o);
    posc   += __shfl_xor(posc, o);
    negs   += __shfl_xor(negs, o);
    negc   += __shfl_xor(negc, o);
    regsum += __shfl_xor(regsum, o);
  }
  if (lane == 0) {
    red[wave][0] = bsum; red[wave][1] = poss; red[wave][2] = posc;
    red[wave][3] = negs; red[wave][4] = negc; red[wave][5] = regsum;
  }
  __syncthreads();
  if (t == 0) {
    float s0=0.f,s1=0.f,s2=0.f,s3=0.f,s4=0.f,s5=0.f;
    for (int w = 0; w < 8; ++w) {
      s0 += red[w][0]; s1 += red[w][1]; s2 += red[w][2];
      s3 += red[w][3]; s4 += red[w][4]; s5 += red[w][5];
    }
    atomicAdd(&ws[3], s0);
    atomicAdd(&ws[4 + b], s1);
    atomicAdd(&ws[20 + b], s2);
    atomicAdd(&ws[36 + b], s3);
    atomicAdd(&ws[52 + b], s4);
    if (diag) atomicAdd(&ws[1], s5);
  }
}

__global__ void finalize(const float* __restrict__ ws, float* __restrict__ out) {
  if (threadIdx.x != 0 || blockIdx.x != 0) return;
  float coord = ws[0] / 32768.f;
  float reg   = ws[1] / 2097152.f;
  float cntl  = ws[2] / 16.f;
  float edge  = ws[3] / 16777216.f;
  float contra = 0.f;
  for (int b = 0; b < 16; ++b) {
    float p = ws[4 + b]  / fmaxf(ws[20 + b], 1.f);
    float n = ws[36 + b] / fmaxf(ws[52 + b], 1.f);
    contra += p + n;
  }
  contra *= (1.f / 16.f);
  float total = coord + 2.f * edge + 0.1f * cntl + 0.001f * reg + 0.1f * contra;
  out[0] = total; out[1] = coord; out[2] = edge;
  out[3] = cntl;  out[4] = reg;   out[5] = contra;
}

extern "C" void kernel_launch(void* const* d_in, const int* in_sizes, int n_in,
                              void* d_out, int out_size, void* d_ws, size_t ws_size,
                              hipStream_t stream) {
  (void)in_sizes; (void)n_in; (void)out_size; (void)ws_size;
  const float* pcoord = (const float*)d_in[0];
  const float* pts    = (const float*)d_in[1];
  const float* logits = (const float*)d_in[2];
  const float* adj    = (const float*)d_in[3];
  const float* masks  = (const float*)d_in[4];
  const float* pcount = (const float*)d_in[5];
  const float* nf     = (const float*)d_in[6];
  float* ws  = (float*)d_ws;
  float* out = (float*)d_out;

  hipMemsetAsync(ws, 0, 68 * sizeof(float), stream);
  small_losses<<<16, 256, 0, stream>>>(pcoord, pts, masks, pcount, ws);
  fused_gram_bce<<<NBLK, 512, 0, stream>>>(logits, adj, nf, ws);
  finalize<<<1, 64, 0, stream>>>(ws, out);
}